// Round 3
// baseline (1981.643 us; speedup 1.0000x reference)
//
#include <hip/hip_runtime.h>
#include <hip/hip_bf16.h>
#include <stdint.h>

#define T_TOK 16384
#define D_DIM 2048
#define F_DIM 5504
#define PCNT  4096   // tokens per chunk (4 chunks)

typedef unsigned short u16;
typedef __attribute__((ext_vector_type(8))) short s16x8;      // 8 bf16 (4 VGPR) MFMA frag
typedef __attribute__((ext_vector_type(8))) unsigned short u16x8;
typedef __attribute__((ext_vector_type(4))) float f32x4;

#define AS1 __attribute__((address_space(1)))
#define AS3 __attribute__((address_space(3)))

__device__ __forceinline__ void gload_lds16(const void* g, u16* l) {
    // 16B-wide direct global->LDS. LDS dest is wave-uniform base + lane*16.
    __builtin_amdgcn_global_load_lds((const AS1 uint32_t*)g, (AS3 uint32_t*)l, 16, 0, 0);
}

__device__ __forceinline__ u16 f32_to_bf16_rne(float f) {
    union { float f; uint32_t u; } v; v.f = f;
    const uint32_t u = v.u;
    return (u16)((u + 0x7FFFu + ((u >> 16) & 1u)) >> 16);
}

// ---------------------------------------------------------------------------
// Kernel 0: detect mask layout (bool8 vs int32), then stable partition of
// token ids. perm[0..nG) = gen tokens, perm[nG..T) = und. meta[0] = nG.
// ---------------------------------------------------------------------------
__global__ void scan_kernel(const void* __restrict__ mask, int* __restrict__ perm,
                            int* __restrict__ meta) {
    __shared__ int cnt[256];
    __shared__ int flag;
    const int t = threadIdx.x;
    if (t == 0) flag = 0;
    __syncthreads();
    // Detector: read only the first 16384 bytes (safe under both layouts).
    // int32 0/1 values have zero bytes at offsets %4 != 0; bool8 does not.
    const unsigned char* mb = (const unsigned char*)mask;
    const int b0 = t << 6;
    int f = 0;
    for (int i = 0; i < 64; ++i) if ((i & 3) != 0) f |= mb[b0 + i];
    if (f) atomicOr(&flag, 1);
    __syncthreads();
    const bool isByte = (flag != 0);

    const int base = t << 6;                 // 64 tokens per thread
    unsigned long long bits = 0;
    if (isByte) {
        for (int i = 0; i < 64; ++i) if (mb[base + i]) bits |= 1ull << i;
    } else {
        const int* mi = (const int*)mask;
        for (int i = 0; i < 64; ++i) if (mi[base + i] != 0) bits |= 1ull << i;
    }
    const int c = __popcll(bits);
    cnt[t] = c;
    __syncthreads();
    for (int off = 1; off < 256; off <<= 1) {   // Hillis-Steele inclusive scan
        int add = (t >= off) ? cnt[t - off] : 0;
        __syncthreads();
        cnt[t] += add;
        __syncthreads();
    }
    const int nG = cnt[255];
    int genPos = cnt[t] - c;                 // exclusive prefix of gen
    int undPos = nG + base - genPos;
    for (int i = 0; i < 64; ++i) {
        const int tokid = base + i;
        if ((bits >> i) & 1ull) perm[genPos++] = tokid;
        else                    perm[undPos++] = tokid;
    }
    if (t == 0) meta[0] = nG;
}

// ---------------------------------------------------------------------------
// Kernel 1: fp32 src[R][C] -> bf16 dst[C][R] (convert + transpose), 64x64
// tiles, 256 threads. R, C multiples of 64 (2048 / 5504).
// ---------------------------------------------------------------------------
__global__ __launch_bounds__(256) void cvtT_kernel(const float* __restrict__ src,
                                                   u16* __restrict__ dst,
                                                   int R, int C) {
    __shared__ u16 tile[64][65];
    const int c0 = blockIdx.x << 6;
    const int r0 = blockIdx.y << 6;
    const int t = threadIdx.x;
    const int rb = t >> 4;                   // 0..15
    const int c4 = (t & 15) << 2;            // 0..60
    #pragma unroll
    for (int p = 0; p < 4; ++p) {
        const int row = (p << 4) + rb;
        const float4 v = *(const float4*)(src + (long)(r0 + row) * C + c0 + c4);
        tile[row][c4 + 0] = f32_to_bf16_rne(v.x);
        tile[row][c4 + 1] = f32_to_bf16_rne(v.y);
        tile[row][c4 + 2] = f32_to_bf16_rne(v.z);
        tile[row][c4 + 3] = f32_to_bf16_rne(v.w);
    }
    __syncthreads();
    const int cc = t >> 2;                   // 0..63 (output row = src col)
    const int rg = (t & 3) << 4;             // 0,16,32,48
    u16x8 o0, o1;
    #pragma unroll
    for (int i = 0; i < 8; ++i) o0[i] = tile[rg + i][cc];
    #pragma unroll
    for (int i = 0; i < 8; ++i) o1[i] = tile[rg + 8 + i][cc];
    u16* d = dst + (long)(c0 + cc) * R + r0 + rg;
    *(u16x8*)d       = o0;
    *(u16x8*)(d + 8) = o1;
}

// ---------------------------------------------------------------------------
// Kernel 2: fp32 -> bf16 elementwise (for X). n4 = elems/4.
// ---------------------------------------------------------------------------
__global__ __launch_bounds__(256) void cvtX_kernel(const float* __restrict__ src,
                                                   u16* __restrict__ dst, int n4) {
    int i = blockIdx.x * 256 + threadIdx.x;
    const int stride = gridDim.x * 256;
    for (; i < n4; i += stride) {
        const float4 v = ((const float4*)src)[i];
        ushort4 o;
        o.x = f32_to_bf16_rne(v.x);
        o.y = f32_to_bf16_rne(v.y);
        o.z = f32_to_bf16_rne(v.z);
        o.w = f32_to_bf16_rne(v.w);
        ((ushort4*)dst)[i] = o;
    }
}

// ---------------------------------------------------------------------------
// GEMM1: H[p-P0][f] = silu(X[tok]·Wg[:,f]) * (X[tok]·Wu[:,f]), tok = perm[p],
// p in [P0, P0+PCNT). 128x128 tile per B-matrix, BK=64, 4 waves (2x2),
// 16x16x32 bf16 MFMA. Weights pre-transposed bf16 [F][D].
// ---------------------------------------------------------------------------
__global__ __launch_bounds__(256, 2) void gemm1_kernel(
    const u16* __restrict__ X,                                    // bf16 [T][D]
    const u16* __restrict__ WgtU, const u16* __restrict__ WupU,   // und, [F][D]
    const u16* __restrict__ WgtG, const u16* __restrict__ WupG,   // gen, [F][D]
    const int* __restrict__ perm, const int* __restrict__ meta,
    u16* __restrict__ H, int P0)
{
    __shared__ u16 As[128 * 64];
    __shared__ u16 Bg[128 * 64];
    __shared__ u16 Bu[128 * 64];

    const int nG = meta[0];
    const int genHi = min(nG, P0 + PCNT);
    const int nGc = max(0, genHi - P0);          // gen rows in this chunk
    const int nGenTiles = (nGc + 127) >> 7;
    const int mt = blockIdx.y;
    int rowStartP, validRows;
    const u16 *Gt, *Ut;
    if (mt < nGenTiles) {
        rowStartP = P0 + (mt << 7);
        validRows = min(128, nGc - (mt << 7));
        Gt = WgtG; Ut = WupG;
    } else {
        const int nUc = PCNT - nGc;
        const int j = mt - nGenTiles;
        if (j >= ((nUc + 127) >> 7)) return;     // uniform early-exit (no barriers yet)
        rowStartP = P0 + nGc + (j << 7);
        validRows = min(128, nUc - (j << 7));
        Gt = WgtU; Ut = WupU;
    }
    const int n0   = blockIdx.x << 7;
    const int tid  = threadIdx.x;
    const int lane = tid & 63;
    const int wid  = tid >> 6;

    long aOff[4], bOff[4];
    {
        const int colB   = (lane & 7) << 4;               // byte col in 128B k-row
        const int subRow = (wid << 3) + (lane >> 3);      // 0..31
        #pragma unroll
        for (int r = 0; r < 4; ++r) {
            const int row = (r << 5) + subRow;            // 0..127
            const int pr  = min(row, validRows - 1);      // clamp padding rows
            const int tok = perm[rowStartP + pr];
            aOff[r] = (long)tok * (D_DIM * 2) + colB;
            bOff[r] = (long)(n0 + row) * (D_DIM * 2) + colB;
        }
    }

    const int wm = wid >> 1, wn = wid & 1;
    const int lr = lane & 15, lh = lane >> 4;
    const u16* aRd = As + ((wm << 6) + lr) * 64 + (lh << 3);
    const u16* gRd = Bg + ((wn << 6) + lr) * 64 + (lh << 3);
    const u16* uRd = Bu + ((wn << 6) + lr) * 64 + (lh << 3);

    f32x4 accG[4][4], accU[4][4];
    const f32x4 z = {0.f, 0.f, 0.f, 0.f};
    #pragma unroll
    for (int i = 0; i < 4; ++i)
        #pragma unroll
        for (int j = 0; j < 4; ++j) { accG[i][j] = z; accU[i][j] = z; }

    const char* Xb = (const char*)X;
    const char* Gb = (const char*)Gt;
    const char* Ub = (const char*)Ut;

    #pragma unroll 1
    for (int kt = 0; kt < D_DIM / 64; ++kt) {
        __syncthreads();                       // prev compute done reading LDS
        #pragma unroll
        for (int r = 0; r < 4; ++r) {
            const int ldsOff = (r << 11) + (wid << 9);   // elements; wave-uniform
            gload_lds16(Xb + aOff[r], (u16*)As + ldsOff);
            gload_lds16(Gb + bOff[r], (u16*)Bg + ldsOff);
            gload_lds16(Ub + bOff[r], (u16*)Bu + ldsOff);
            aOff[r] += 128;                    // BK*2 bytes
            bOff[r] += 128;
        }
        __syncthreads();                       // barrier drains vmcnt
        #pragma unroll
        for (int ks = 0; ks < 2; ++ks) {
            s16x8 af[4], gf[4], uf[4];
            #pragma unroll
            for (int i = 0; i < 4; ++i) af[i] = *(const s16x8*)(aRd + (i << 10) + (ks << 5));
            #pragma unroll
            for (int i = 0; i < 4; ++i) gf[i] = *(const s16x8*)(gRd + (i << 10) + (ks << 5));
            #pragma unroll
            for (int i = 0; i < 4; ++i) uf[i] = *(const s16x8*)(uRd + (i << 10) + (ks << 5));
            #pragma unroll
            for (int i = 0; i < 4; ++i)
                #pragma unroll
                for (int j = 0; j < 4; ++j) {
                    accG[i][j] = __builtin_amdgcn_mfma_f32_16x16x32_bf16(af[i], gf[j], accG[i][j], 0, 0, 0);
                    accU[i][j] = __builtin_amdgcn_mfma_f32_16x16x32_bf16(af[i], uf[j], accU[i][j], 0, 0, 0);
                }
        }
    }

    // Epilogue: h = silu(g)*u, store bf16. C/D map: col=lane&15, row=(lane>>4)*4+reg.
    const int rowB = (wm << 6) + (lh << 2);
    const int colG = n0 + (wn << 6) + lr;
    #pragma unroll
    for (int i = 0; i < 4; ++i)
        #pragma unroll
        for (int j = 0; j < 4; ++j)
            #pragma unroll
            for (int q = 0; q < 4; ++q) {
                const int row = rowB + (i << 4) + q;
                if (row < validRows) {
                    const float g = accG[i][j][q];
                    const float u = accU[i][j][q];
                    const float h = (g / (1.f + __expf(-g))) * u;
                    H[(long)(rowStartP + row - P0) * F_DIM + colG + (j << 4)] = f32_to_bf16_rne(h);
                }
            }
}

// ---------------------------------------------------------------------------
// GEMM2: out[perm[p]][d] = H[p-P0]·Wd[:,d], fp32 out. K=F=5504 (86 iters),
// Wdown bf16 [D][F]. Scatter-store through perm.
// ---------------------------------------------------------------------------
__global__ __launch_bounds__(256, 2) void gemm2_kernel(
    const u16* __restrict__ H,                                   // bf16 [PCNT][F]
    const u16* __restrict__ WdU, const u16* __restrict__ WdG,    // bf16 [D][F]
    const int* __restrict__ perm, const int* __restrict__ meta,
    float* __restrict__ Out, int P0)
{
    __shared__ u16 As[128 * 64];
    __shared__ u16 Bs[128 * 64];

    const int nG = meta[0];
    const int genHi = min(nG, P0 + PCNT);
    const int nGc = max(0, genHi - P0);
    const int nGenTiles = (nGc + 127) >> 7;
    const int mt = blockIdx.y;
    int rowStartP, validRows;
    const u16* Wd;
    if (mt < nGenTiles) {
        rowStartP = P0 + (mt << 7);
        validRows = min(128, nGc - (mt << 7));
        Wd = WdG;
    } else {
        const int nUc = PCNT - nGc;
        const int j = mt - nGenTiles;
        if (j >= ((nUc + 127) >> 7)) return;
        rowStartP = P0 + nGc + (j << 7);
        validRows = min(128, nUc - (j << 7));
        Wd = WdU;
    }
    const int n0   = blockIdx.x << 7;
    const int tid  = threadIdx.x;
    const int lane = tid & 63;
    const int wid  = tid >> 6;

    long aOff[4], bOff[4];
    {
        const int colB   = (lane & 7) << 4;
        const int subRow = (wid << 3) + (lane >> 3);
        #pragma unroll
        for (int r = 0; r < 4; ++r) {
            const int row = (r << 5) + subRow;
            const long hr = min(rowStartP + row, (long)P0 + PCNT - 1) - P0; // in-chunk
            aOff[r] = hr * (F_DIM * 2) + colB;
            bOff[r] = (long)(n0 + row) * (F_DIM * 2) + colB;
        }
    }

    const int wm = wid >> 1, wn = wid & 1;
    const int lr = lane & 15, lh = lane >> 4;
    const u16* aRd = As + ((wm << 6) + lr) * 64 + (lh << 3);
    const u16* bRd = Bs + ((wn << 6) + lr) * 64 + (lh << 3);

    f32x4 acc[4][4];
    const f32x4 z = {0.f, 0.f, 0.f, 0.f};
    #pragma unroll
    for (int i = 0; i < 4; ++i)
        #pragma unroll
        for (int j = 0; j < 4; ++j) acc[i][j] = z;

    const char* Hb = (const char*)H;
    const char* Wb = (const char*)Wd;

    #pragma unroll 1
    for (int kt = 0; kt < F_DIM / 64; ++kt) {
        __syncthreads();
        #pragma unroll
        for (int r = 0; r < 4; ++r) {
            const int ldsOff = (r << 11) + (wid << 9);
            gload_lds16(Hb + aOff[r], (u16*)As + ldsOff);
            gload_lds16(Wb + bOff[r], (u16*)Bs + ldsOff);
            aOff[r] += 128;
            bOff[r] += 128;
        }
        __syncthreads();
        #pragma unroll
        for (int ks = 0; ks < 2; ++ks) {
            s16x8 af[4], bf[4];
            #pragma unroll
            for (int i = 0; i < 4; ++i) af[i] = *(const s16x8*)(aRd + (i << 10) + (ks << 5));
            #pragma unroll
            for (int i = 0; i < 4; ++i) bf[i] = *(const s16x8*)(bRd + (i << 10) + (ks << 5));
            #pragma unroll
            for (int i = 0; i < 4; ++i)
                #pragma unroll
                for (int j = 0; j < 4; ++j)
                    acc[i][j] = __builtin_amdgcn_mfma_f32_16x16x32_bf16(af[i], bf[j], acc[i][j], 0, 0, 0);
        }
    }

    const int rowB = (wm << 6) + (lh << 2);
    const int colG = n0 + (wn << 6) + lr;
    #pragma unroll
    for (int i = 0; i < 4; ++i)
        #pragma unroll
        for (int j = 0; j < 4; ++j)
            #pragma unroll
            for (int q = 0; q < 4; ++q) {
                const int row = rowB + (i << 4) + q;
                if (row < validRows) {
                    const int tok = perm[rowStartP + row];   // broadcast across 16 lanes
                    Out[(long)tok * D_DIM + colG + (j << 4)] = acc[i][j][q];
                }
            }
}

// ---------------------------------------------------------------------------
extern "C" void kernel_launch(void* const* d_in, const int* in_sizes, int n_in,
                              void* d_out, int out_size, void* d_ws, size_t ws_size,
                              hipStream_t stream) {
    (void)in_sizes; (void)n_in; (void)out_size; (void)ws_size;
    const float* X       = (const float*)d_in[0];
    const float* undGate = (const float*)d_in[1];
    const float* undUp   = (const float*)d_in[2];
    const float* undDown = (const float*)d_in[3];
    const float* genGate = (const float*)d_in[4];
    const float* genUp   = (const float*)d_in[5];
    const float* genDown = (const float*)d_in[6];
    const void*  mask    = d_in[7];              // bool8 or int32, detected on device

    char* ws = (char*)d_ws;
    int* meta = (int*)ws;                        // [0]: nG
    int* perm = (int*)(ws + 256);                // T ints
    const size_t WSZ = (size_t)D_DIM * F_DIM * 2;   // bf16 weight matrix: 22,544,384 B
    u16* undGateT = (u16*)(ws + 65792 + 0 * WSZ);
    u16* undUpT   = (u16*)(ws + 65792 + 1 * WSZ);
    u16* genGateT = (u16*)(ws + 65792 + 2 * WSZ);
    u16* genUpT   = (u16*)(ws + 65792 + 3 * WSZ);
    u16* undDownT = (u16*)(ws + 65792 + 4 * WSZ);
    u16* genDownT = (u16*)(ws + 65792 + 5 * WSZ);
    u16* Xb       = (u16*)(ws + 65792 + 6 * WSZ);                     // [T][D] bf16, 67 MB
    u16* H        = (u16*)(ws + 65792 + 6 * WSZ + (size_t)T_TOK * D_DIM * 2); // [PCNT][F] bf16, 45 MB

    scan_kernel<<<1, 256, 0, stream>>>(mask, perm, meta);

    // fp32 (D,F) -> bf16 (F,D) for gate/up; fp32 (F,D) -> bf16 (D,F) for down.
    dim3 tg1(F_DIM / 64, D_DIM / 64);
    cvtT_kernel<<<tg1, 256, 0, stream>>>(undGate, undGateT, D_DIM, F_DIM);
    cvtT_kernel<<<tg1, 256, 0, stream>>>(undUp,   undUpT,   D_DIM, F_DIM);
    cvtT_kernel<<<tg1, 256, 0, stream>>>(genGate, genGateT, D_DIM, F_DIM);
    cvtT_kernel<<<tg1, 256, 0, stream>>>(genUp,   genUpT,   D_DIM, F_DIM);
    dim3 tg2(D_DIM / 64, F_DIM / 64);
    cvtT_kernel<<<tg2, 256, 0, stream>>>(undDown, undDownT, F_DIM, D_DIM);
    cvtT_kernel<<<tg2, 256, 0, stream>>>(genDown, genDownT, F_DIM, D_DIM);

    cvtX_kernel<<<2048, 256, 0, stream>>>(X, Xb, T_TOK * D_DIM / 4);

    // Chunked over permuted tokens; +1 M-tile absorbs the gen/und boundary.
    for (int c = 0; c < T_TOK / PCNT; ++c) {
        const int P0 = c * PCNT;
        gemm1_kernel<<<dim3(F_DIM / 128, PCNT / 128 + 1), 256, 0, stream>>>(
            Xb, undGateT, undUpT, genGateT, genUpT, perm, meta, H, P0);
        gemm2_kernel<<<dim3(D_DIM / 128, PCNT / 128 + 1), 256, 0, stream>>>(
            H, undDownT, genDownT, perm, meta, (float*)d_out, P0);
    }
}